// Round 1
// baseline (292.379 us; speedup 1.0000x reference)
//
#include <hip/hip_runtime.h>
#include <hip/hip_bf16.h>
#include <math.h>

// Problem constants
#define BATCH 64
#define SEQ   512
#define DIM   768
#define NW    256              // MAX_WORDS
#define NT    (BATCH * NW)     // 16384 tokens
#define KDIM  1536             // 2*DIM
#define HID   256              // router hidden
#define NL    7                // num labels

// GEMM tiling
#define BM  32
#define BK  64
#define BKP 72                 // padded LDS row stride (bf16) -> 144 B
#define NKT (KDIM / BK)        // 24

typedef __bf16 bf16_t;
typedef bf16_t bf16x4 __attribute__((ext_vector_type(4)));
typedef bf16_t bf16x8 __attribute__((ext_vector_type(8)));
typedef float  f32x4  __attribute__((ext_vector_type(4)));

// ---------------------------------------------------------------------------
// Kernel 1 (fused): convert router_w1 -> bf16 K-major tiles  AND  build the
// starts table. blocks 0..191 = w1 convert; blocks 192..319 = starts.
// ---------------------------------------------------------------------------
__global__ __launch_bounds__(256) void prep_kernel(
    const float* __restrict__ w1, bf16_t* __restrict__ w1t,
    const int* __restrict__ idh, const int* __restrict__ idr,
    int* __restrict__ starts)
{
    if (blockIdx.x < 192) {
        int kc = blockIdx.x >> 3;        // 0..23
        int kg = blockIdx.x & 7;         // 0..7
        int n  = threadIdx.x;            // 0..255
        bf16x8 v;
        #pragma unroll
        for (int j = 0; j < 8; j++)
            v[j] = (bf16_t)w1[(size_t)(kc * 64 + kg * 8 + j) * HID + n];
        *(bf16x8*)(w1t + (size_t)kc * (HID * BK) + n * BK + kg * 8) = v;
    } else {
        int blk = blockIdx.x - 192;      // 0..127 = 2 tensors x 64 batches
        int t = blk >> 6;
        int b = blk & 63;
        const int* ids = (t ? idr : idh) + b * SEQ;
        int w = threadIdx.x;
        int lo = 0, hi = SEQ;
        while (lo < hi) {
            int m = (lo + hi) >> 1;
            if (ids[m] < w) lo = m + 1; else hi = m;
        }
        int* row = starts + blk * 257;
        row[w] = lo;
        if (w == 0) row[256] = SEQ;
    }
}

// ---------------------------------------------------------------------------
// Kernel 2: segment-mean align — STREAMING row-walk rewrite.
// Wave-task = (b, tensor, 16-word range, 256-col chunk): 64*2*16*3 = 6144
// tasks -> grid 1536 x 256 (4 waves/block).
// Each wave walks its contiguous subtoken row range [st[w0], st[w0+16])
// sequentially, EXACTLY ONCE, in double-buffered 8-row register chunks
// (8 loads always in flight while the previous 8 are drained). Word
// boundaries (wave-uniform, from starts) trigger the mean+bf16 store.
// Removes the old 3x load amplification (always-6-rows for avg n=2) and
// structurally guarantees MLP (the chunk buffers force ~96 VGPRs).
// ---------------------------------------------------------------------------
#define WPT 16                 // words per task
#define CH  8                  // rows per register chunk

#define LOADCH(buf, cs_) {                                                    \
    _Pragma("unroll")                                                         \
    for (int i_ = 0; i_ < CH; i_++) {                                         \
        int s_ = (cs_) + i_;                                                  \
        s_ = s_ < hi ? s_ : hi - 1;            /* clamp: L1-hit dupes */      \
        buf[i_] = src[(size_t)s_ * 192 + lane];                               \
    } }

#define EMIT_ZERO(wid) *(bf16x4*)(dst + (size_t)(wid) * KDIM + lane * 4) = zero4;

#define DRAIN(buf, cs_) {                                                     \
    _Pragma("unroll")                                                         \
    for (int i_ = 0; i_ < CH; i_++) {                                         \
        int s_ = (cs_) + i_;                                                  \
        if (s_ < hi) {                                                        \
            acc[0] += buf[i_][0]; acc[1] += buf[i_][1];                       \
            acc[2] += buf[i_][2]; acc[3] += buf[i_][3];                       \
            if (s_ + 1 == nb) {                /* word w complete */          \
                float invn = 1.0f / (float)(nb - wstart);                     \
                bf16x4 o;                                                     \
                o[0] = (bf16_t)(acc[0] * invn); o[1] = (bf16_t)(acc[1] * invn);\
                o[2] = (bf16_t)(acc[2] * invn); o[3] = (bf16_t)(acc[3] * invn);\
                *(bf16x4*)(dst + (size_t)w * KDIM + lane * 4) = o;            \
                acc = (f32x4){0.f, 0.f, 0.f, 0.f};                            \
                w++; wstart = nb;                                             \
                while (w < WPT) {              /* emit empty words */         \
                    int nb2 = st[w + 1];                                      \
                    if (nb2 > wstart) { nb = nb2; break; }                    \
                    EMIT_ZERO(w); w++;                                        \
                }                                                             \
            }                                                                 \
        }                                                                     \
    } }

__global__ __launch_bounds__(256, 2) void align_kernel(
    const float* __restrict__ hh, const float* __restrict__ hr,
    const int* __restrict__ starts, bf16_t* __restrict__ X)
{
    int tid  = threadIdx.x;
    int lane = tid & 63;
    int wv   = tid >> 6;
    int task = blockIdx.x * 4 + wv;      // 0..6143
    int dc   = task % 3;                 // col chunk: floats [dc*256, dc*256+256)
    int q    = task / 3;                 // 0..2047
    int wb   = q & 15;                   // 16-word block index
    int t    = (q >> 4) & 1;
    int b    = q >> 5;

    const int*   st  = starts + (t * 64 + b) * 257 + wb * WPT;   // st[0..WPT]
    const f32x4* src = (const f32x4*)((t ? hr : hh)
                        + (size_t)b * SEQ * DIM + dc * 256);     // row s: +s*192+lane
    bf16_t*      dst = X + (size_t)b * NW * KDIM + (size_t)wb * WPT * KDIM
                         + t * DIM + dc * 256;                   // word w: +w*KDIM+lane*4

    bf16x4 zero4 = {};
    int lo = st[0];
    int hi = st[WPT];

    int w  = 0;
    int nb = st[1];
    // leading (and possibly all) empty words: boundary == lo
    while (nb == lo) {
        EMIT_ZERO(w);
        w++;
        if (w == WPT) break;
        nb = st[w + 1];
    }

    if (lo < hi) {
        f32x4 acc = {0.f, 0.f, 0.f, 0.f};
        int wstart = lo;                 // == st[w] after the empty sweep
        f32x4 bufA[CH], bufB[CH];
        LOADCH(bufA, lo);
        int cs = lo;
        for (;;) {
            LOADCH(bufB, cs + CH);       // prefetch next chunk
            DRAIN(bufA, cs);             // accumulate + boundary emits
            cs += CH;
            if (cs >= hi) break;
            LOADCH(bufA, cs + CH);
            DRAIN(bufB, cs);
            cs += CH;
            if (cs >= hi) break;
        }
    }
}

// ---------------------------------------------------------------------------
// Kernel 3: router GEMM (bf16 MFMA) via LDS -> alpha.  (unchanged)
// ---------------------------------------------------------------------------
__global__ __launch_bounds__(256) void gemm_alpha_kernel(
    const bf16_t* __restrict__ X, const bf16_t* __restrict__ w1t,
    const float* __restrict__ b1, const float* __restrict__ w2,
    const float* __restrict__ b2, float* __restrict__ out)
{
    __shared__ __align__(16) bf16_t Xs[BM][BKP];
    __shared__ __align__(16) bf16_t Ws[HID][BKP];
    __shared__ float alpha_acc[BM];

    int tid   = threadIdx.x;
    int lane  = tid & 63;
    int wv    = tid >> 6;
    int row16 = lane & 15;
    int quad  = lane >> 4;
    int tok0  = blockIdx.x * BM;

    f32x4 acc[2][4];
    #pragma unroll
    for (int mi = 0; mi < 2; mi++)
        #pragma unroll
        for (int ni = 0; ni < 4; ni++)
            acc[mi][ni] = (f32x4){0.f, 0.f, 0.f, 0.f};

    int xr = tid >> 3;
    int xc = tid & 7;

    for (int kc = 0; kc < NKT; kc++) {
        {
            const uint4* src = (const uint4*)(X + (size_t)(tok0 + xr) * KDIM + kc * BK + xc * 8);
            *(uint4*)(&Xs[xr][xc * 8]) = *src;
        }
        {
            const uint4* srcb = (const uint4*)(w1t + (size_t)kc * (HID * BK));
            #pragma unroll
            for (int i = 0; i < 8; i++) {
                int cidx = tid + i * 256;
                *(uint4*)(&Ws[cidx >> 3][(cidx & 7) * 8]) = srcb[cidx];
            }
        }
        __syncthreads();
        #pragma unroll
        for (int kk2 = 0; kk2 < 2; kk2++) {
            bf16x8 af[2], bfg[4];
            #pragma unroll
            for (int mi = 0; mi < 2; mi++)
                af[mi] = *(const bf16x8*)(&Xs[mi * 16 + row16][kk2 * 32 + quad * 8]);
            #pragma unroll
            for (int ni = 0; ni < 4; ni++)
                bfg[ni] = *(const bf16x8*)(&Ws[wv * 64 + ni * 16 + row16][kk2 * 32 + quad * 8]);
            #pragma unroll
            for (int mi = 0; mi < 2; mi++)
                #pragma unroll
                for (int ni = 0; ni < 4; ni++)
                    acc[mi][ni] = __builtin_amdgcn_mfma_f32_16x16x32_bf16(
                        af[mi], bfg[ni], acc[mi][ni], 0, 0, 0);
        }
        __syncthreads();
    }

    float w2v[4], b1v[4];
    #pragma unroll
    for (int ni = 0; ni < 4; ni++) {
        int col = wv * 64 + ni * 16 + row16;
        w2v[ni] = w2[col];
        b1v[ni] = b1[col];
    }
    if (tid < BM) alpha_acc[tid] = 0.f;
    __syncthreads();

    #pragma unroll
    for (int mi = 0; mi < 2; mi++) {
        #pragma unroll
        for (int r = 0; r < 4; r++) {
            float p = 0.f;
            #pragma unroll
            for (int ni = 0; ni < 4; ni++) {
                float v = acc[mi][ni][r] + b1v[ni];
                v = v > 0.f ? v : 0.f;
                p += v * w2v[ni];
            }
            p += __shfl_xor(p, 1);
            p += __shfl_xor(p, 2);
            p += __shfl_xor(p, 4);
            p += __shfl_xor(p, 8);
            if (row16 == 0)
                atomicAdd(&alpha_acc[mi * 16 + quad * 4 + r], p);
        }
    }
    __syncthreads();
    if (tid < BM) {
        float a = 1.f / (1.f + expf(-(alpha_acc[tid] + b2[0])));
        out[(size_t)NT * NL + tok0 + tid] = a;
    }
}

// ---------------------------------------------------------------------------
// Kernel 4: blend + head + l2. 8 tokens per wave. Grid 512. (unchanged)
// ---------------------------------------------------------------------------
__global__ __launch_bounds__(256) void blend_kernel(
    const bf16_t* __restrict__ X, const float* __restrict__ hw,
    const float* __restrict__ hb, float* __restrict__ out)
{
    __shared__ float hws[NL * DIM];       // [l][d]
    int tid  = threadIdx.x;
    int lane = tid & 63;
    int wv   = tid >> 6;

    for (int i = tid; i < DIM * NL; i += 256) {
        int d = i / NL, l = i - d * NL;
        hws[l * DIM + d] = hw[i];
    }
    __syncthreads();

    int g   = lane >> 3;
    int u   = lane & 7;
    int tok = blockIdx.x * 32 + wv * 8 + g;

    float a = out[(size_t)NT * NL + tok];
    const bf16_t* xrow = X + (size_t)tok * KDIM;

    float lg[NL] = {0.f, 0.f, 0.f, 0.f, 0.f, 0.f, 0.f};
    float l2 = 0.f;

    #pragma unroll
    for (int k = 0; k < 12; k++) {
        int d0 = (k * 8 + u) * 8;
        bf16x8 hp = *(const bf16x8*)(xrow + d0);
        bf16x8 rp = *(const bf16x8*)(xrow + DIM + d0);
        float bl[8];
        #pragma unroll
        for (int e = 0; e < 8; e++) {
            float hhv = (float)hp[e];
            float hrv = (float)rp[e];
            float df  = hhv - hrv;
            bl[e] = fmaf(a, df, hrv);
            l2 = fmaf(df, df, l2);
        }
        #pragma unroll
        for (int l = 0; l < NL; l++) {
            f32x4 wA = *(const f32x4*)(&hws[l * DIM + d0]);
            f32x4 wB = *(const f32x4*)(&hws[l * DIM + d0 + 4]);
            lg[l] += bl[0]*wA[0] + bl[1]*wA[1] + bl[2]*wA[2] + bl[3]*wA[3]
                   + bl[4]*wB[0] + bl[5]*wB[1] + bl[6]*wB[2] + bl[7]*wB[3];
        }
    }

    #pragma unroll
    for (int off = 1; off < 8; off <<= 1) {
        #pragma unroll
        for (int l = 0; l < NL; l++) lg[l] += __shfl_xor(lg[l], off);
        l2 += __shfl_xor(l2, off);
    }

    if (u < NL) {
        float v = (u == 0) ? lg[0] : (u == 1) ? lg[1] : (u == 2) ? lg[2]
                : (u == 3) ? lg[3] : (u == 4) ? lg[4] : (u == 5) ? lg[5] : lg[6];
        out[(size_t)tok * NL + u] = v + hb[u];
    } else {
        out[(size_t)NT * NL + NT + tok] = sqrtf(l2);
    }
}

// ---------------------------------------------------------------------------
extern "C" void kernel_launch(void* const* d_in, const int* in_sizes, int n_in,
                              void* d_out, int out_size, void* d_ws, size_t ws_size,
                              hipStream_t stream)
{
    const float* hh  = (const float*)d_in[0];
    const float* hr  = (const float*)d_in[1];
    const int*   idh = (const int*)d_in[2];
    const int*   idr = (const int*)d_in[3];
    const float* w1  = (const float*)d_in[5];
    const float* b1  = (const float*)d_in[6];
    const float* w2  = (const float*)d_in[7];
    const float* b2  = (const float*)d_in[8];
    const float* hw  = (const float*)d_in[9];
    const float* hb  = (const float*)d_in[10];
    float* out = (float*)d_out;

    bf16_t* X      = (bf16_t*)d_ws;                        // 50.33 MB
    bf16_t* w1t    = X + (size_t)NT * KDIM;                // 0.79 MB (tiled)
    int*    starts = (int*)(w1t + (size_t)NKT * HID * BK); // 263 KB

    prep_kernel<<<320, 256, 0, stream>>>(w1, w1t, idh, idr, starts);
    align_kernel<<<1536, 256, 0, stream>>>(hh, hr, starts, X);
    gemm_alpha_kernel<<<NT / BM, 256, 0, stream>>>(X, w1t, b1, w2, b2, out);
    blend_kernel<<<512, 256, 0, stream>>>(X, hw, hb, out);
}